// Round 7
// baseline (168.556 us; speedup 1.0000x reference)
//
#include <hip/hip_runtime.h>
#include <hip/hip_bf16.h>

// Pipeline: weight prep -> qproj GEMM (f32 A, fused cast) -> conv-as-GEMM
//           (im2col f32 gather, split-K=4, partials in d_out) -> fused
//           reduce+bias+LN -> kvproj GEMM -> fused attention -> out proj GEMM.
// GEMM v2: double-buffered LDS + T14 reg-staged pipeline (issue-early /
//   write-late, ONE barrier per K-step) + XCD-chunked block swizzle so
//   A-slices are single-XCD and B stays L2-resident.
// Attention v5: zero LDS/barriers, register P, permuted V, 2-deep prefetch.
// Workspace requirement: ~26 MB.

using bf16 = __hip_bfloat16;
using f32x4 = __attribute__((ext_vector_type(4))) float;
using bf16x8 = __attribute__((ext_vector_type(8))) short;

#define DEVINL __device__ __forceinline__

DEVINL f32x4 mfma16(bf16x8 a, bf16x8 b, f32x4 c) {
    return __builtin_amdgcn_mfma_f32_16x16x32_bf16(a, b, c, 0, 0, 0);
}

DEVINL unsigned short f2bf(float f) {
    union { float f; unsigned u; } x; x.f = f;
    unsigned u = x.u;
    u += 0x7fffu + ((u >> 16) & 1u);   // RNE
    return (unsigned short)(u >> 16);
}

// pack two f32 -> two bf16 (RTZ) in one v_perm: low16 = trunc(a), high16 = trunc(b)
DEVINL unsigned pk_rtz(float a, float b) {
    return __builtin_amdgcn_perm(__float_as_uint(b), __float_as_uint(a), 0x07060302u);
}

DEVINL float ex2(float x) { return __builtin_amdgcn_exp2f(x); }   // raw v_exp_f32

// ---------------- prep kernels ----------------

// out[n*K + k] = in[k*N + n]  (weight [K,N] -> [N,K] bf16)
__global__ __launch_bounds__(256) void transpose_cast_kernel(const float* __restrict__ in,
                                                             bf16* __restrict__ out, int K, int N) {
    int idx = blockIdx.x * 256 + threadIdx.x;
    if (idx >= K * N) return;
    int k = idx % K, n = idx / K;
    out[idx] = __float2bfloat16(in[k * N + n]);
}

// wcv[o*4096 + dydx*256 + c] = sr_w[o][c][dy][dx]   (OIHW, 4x4)
__global__ __launch_bounds__(256) void conv_w_kernel(const float* __restrict__ sr_w,
                                                     bf16* __restrict__ out) {
    int idx = blockIdx.x * 256 + threadIdx.x;   // exact grid: 4096*256 = 1048576
    int o = idx >> 12, rest = idx & 4095, dydx = rest >> 8, c = rest & 255;
    out[idx] = __float2bfloat16(sr_w[((o << 8) + c) * 16 + dydx]);
}

// ---------------- GEMM ----------------
// C[M,N] = A[M,K] * WT[N,K]^T ; bf16 MFMA, f32 acc. 64x64 tile, BK=64.
// Double-buffered LDS; per K-step: issue loads(t+1)->regs, compute(t),
// convert+write regs->LDS[buf^1], ONE __syncthreads. XCD-chunked swizzle on
// blockIdx.x (tm-major logical order, grid.x % 8 == 0).
// LDS XOR chunk swizzle: element (r,c) at r*64 + ((c>>3)^(r&7))*8 + (c&7).
// AMODE 0: A bf16 row-major. AMODE 1: im2col gather from f32 x [4][16384][256].
// AMODE 2: A f32 row-major (fused cast).
// EMODE 0: out bf16 scaled by SCALE*log2e (qh). EMODE 1: out f32 + bias.
// EMODE 2: kv split -> k per-head [(b*8+h)][key][d] bf16,
//          v transposed+key-PERMUTED [(b*8+h)*32+d][keyp] (PV fragment order).
// EMODE 3: f32 partial (split-K slice blockIdx.y) into outf[ks][4096][256].
template<int AMODE, int EMODE>
__global__ __launch_bounds__(256, 4) void gemm_kernel(
    const void* __restrict__ A, const bf16* __restrict__ WT,
    const float* __restrict__ bias,
    bf16* __restrict__ outb, float* __restrict__ outf, bf16* __restrict__ out2,
    int M, int N, int K, int KS)
{
    __shared__ alignas(16) bf16 As[2][64 * 64];
    __shared__ alignas(16) bf16 Bs[2][64 * 64];
    // XCD-chunked swizzle: XCD (bx%8) gets a contiguous tm-range with all tn.
    const int cpx = gridDim.x >> 3;
    const int bx = (blockIdx.x & 7) * cpx + (blockIdx.x >> 3);
    const int ntn = N >> 6;
    const int tm = bx / ntn, tn = bx % ntn;
    const int tid = threadIdx.x, lane = tid & 63;
    const int wid = tid >> 6, l15 = lane & 15, g = lane >> 4;
    const int wm = (wid >> 1) << 5, wn = (wid & 1) << 5;
    f32x4 acc[2][2] = {};

    // staging coords per 16B chunk p (idx = p*256 + tid)
    int r_[2], cs_[2], dst_[2];
#pragma unroll
    for (int p = 0; p < 2; ++p) {
        int idx = p * 256 + tid;
        r_[p] = idx >> 3;
        cs_[p] = ((idx & 7) ^ (r_[p] & 7)) << 3;   // swizzled source column
        dst_[p] = idx << 3;                         // linear LDS dst
    }

    const int kbeg = blockIdx.y * KS;
    const int nsteps = KS >> 6;

    uint4 br[2];            // staged B chunks (bf16)
    uint4 ar[2];            // staged A chunks (AMODE 0)
    float4 af0[2], af1[2];  // staged A chunks (f32 modes)

    auto issue_loads = [&](int k0) {
#pragma unroll
        for (int p = 0; p < 2; ++p) {
            br[p] = *(const uint4*)&WT[(size_t)(tn * 64 + r_[p]) * K + (k0 + cs_[p])];
            if constexpr (AMODE == 0) {
                ar[p] = *(const uint4*)&((const bf16*)A)[(size_t)(tm * 64 + r_[p]) * K + (k0 + cs_[p])];
            } else {
                const float* Af = (const float*)A;
                const float* src;
                if constexpr (AMODE == 2) {
                    src = &Af[(size_t)(tm * 64 + r_[p]) * K + (k0 + cs_[p])];
                } else {
                    int pr = tm * 64 + r_[p];             // patch index
                    int bb = pr >> 10, pi = pr & 1023;
                    int ii = pi >> 5, jj = pi & 31;
                    int kk2 = k0 + cs_[p];
                    int dydx = kk2 >> 8, cc = kk2 & 255;
                    int dy = dydx >> 2, dx = dydx & 3;
                    int pos = ((ii << 2) + dy) * 128 + (jj << 2) + dx;
                    src = &Af[(size_t)((bb << 14) + pos) * 256 + cc];
                }
                af0[p] = *(const float4*)src;
                af1[p] = *(const float4*)(src + 4);
            }
        }
    };
    auto write_lds = [&](int buf) {
#pragma unroll
        for (int p = 0; p < 2; ++p) {
            *(uint4*)&Bs[buf][dst_[p]] = br[p];
            if constexpr (AMODE == 0) {
                *(uint4*)&As[buf][dst_[p]] = ar[p];
            } else {
                uint4 u;
                u.x = f2bf(af0[p].x) | ((unsigned)f2bf(af0[p].y) << 16);
                u.y = f2bf(af0[p].z) | ((unsigned)f2bf(af0[p].w) << 16);
                u.z = f2bf(af1[p].x) | ((unsigned)f2bf(af1[p].y) << 16);
                u.w = f2bf(af1[p].z) | ((unsigned)f2bf(af1[p].w) << 16);
                *(uint4*)&As[buf][dst_[p]] = u;
            }
        }
    };

    issue_loads(kbeg);
    write_lds(0);
    __syncthreads();

    for (int t = 0; t < nsteps; ++t) {
        const int buf = t & 1;
        if (t + 1 < nsteps) issue_loads(kbeg + (t + 1) * 64);   // overlap with compute
#pragma unroll
        for (int kk = 0; kk < 2; ++kk) {
            const int sw = l15 & 7;
            const int co = ((kk * 4 + g) ^ sw) << 3;
            bf16x8 a0 = *(const bf16x8*)&As[buf][(wm + l15) * 64 + co];
            bf16x8 a1 = *(const bf16x8*)&As[buf][(wm + 16 + l15) * 64 + co];
            bf16x8 b0 = *(const bf16x8*)&Bs[buf][(wn + l15) * 64 + co];
            bf16x8 b1 = *(const bf16x8*)&Bs[buf][(wn + 16 + l15) * 64 + co];
            acc[0][0] = mfma16(a0, b0, acc[0][0]);
            acc[0][1] = mfma16(a0, b1, acc[0][1]);
            acc[1][0] = mfma16(a1, b0, acc[1][0]);
            acc[1][1] = mfma16(a1, b1, acc[1][1]);
        }
        if (t + 1 < nsteps) write_lds(buf ^ 1);   // write-late (T14)
        __syncthreads();
    }

    const float qscale = 0.1767766953f * 1.4426950409f;  // HD^-0.5 * log2(e)
#pragma unroll
    for (int mi = 0; mi < 2; ++mi)
#pragma unroll
    for (int ni = 0; ni < 2; ++ni)
#pragma unroll
    for (int r = 0; r < 4; ++r) {
        int row = tm * 64 + wm + mi * 16 + g * 4 + r;
        int col = tn * 64 + wn + ni * 16 + l15;
        float v = acc[mi][ni][r];
        if constexpr (EMODE == 0) {
            outb[(size_t)row * 256 + col] = __float2bfloat16(v * qscale);
        } else if constexpr (EMODE == 1) {
            outf[(size_t)row * 256 + col] = v + bias[col];
        } else if constexpr (EMODE == 2) {
            int bb = row >> 10, key = row & 1023;
            if (col < 256) {
                int hh = col >> 5, d = col & 31;
                outb[(size_t)(((bb << 3) + hh) * 1024 + key) * 32 + d] = __float2bfloat16(v);
            } else {
                int d = col - 256;
                // key-permuted position within its 32-block: PV B-fragment order
                int c = key & 31;
                int pos = (((c >> 2) & 3) << 3) + ((c >> 4) << 2) + (c & 3);
                int keyp = (key & ~31) | pos;
                out2[(size_t)(((bb << 3) + (d >> 5)) * 32 + (d & 31)) * 1024 + keyp] =
                    __float2bfloat16(v);
            }
        } else {
            outf[((size_t)blockIdx.y * 4096 + row) * 256 + col] = v;
        }
    }
}

// ------- fused split-K reduce + conv bias + LayerNorm (C=256, one wave/row) -------
__global__ __launch_bounds__(256) void ln_kernel(const float* __restrict__ pp,
                                                 const float* __restrict__ cb,
                                                 const float* __restrict__ gw,
                                                 const float* __restrict__ bw,
                                                 bf16* __restrict__ out) {
    int row = blockIdx.x * 4 + (threadIdx.x >> 6);
    int lane = threadIdx.x & 63;
    const size_t base = (size_t)row * 256 + lane * 4;
    float4 v = *(const float4*)&pp[base];
#pragma unroll
    for (int s = 1; s < 4; ++s) {
        const float4 t = *(const float4*)&pp[(size_t)s * (4096 * 256) + base];
        v.x += t.x; v.y += t.y; v.z += t.z; v.w += t.w;
    }
    const float4 cbv = *(const float4*)&cb[lane * 4];
    v.x += cbv.x; v.y += cbv.y; v.z += cbv.z; v.w += cbv.w;

    float s = v.x + v.y + v.z + v.w;
#pragma unroll
    for (int m = 1; m < 64; m <<= 1) s += __shfl_xor(s, m, 64);
    float mu = s * 0.00390625f;
    float d0 = v.x - mu, d1 = v.y - mu, d2 = v.z - mu, d3 = v.w - mu;
    float qv = d0 * d0 + d1 * d1 + d2 * d2 + d3 * d3;
#pragma unroll
    for (int m = 1; m < 64; m <<= 1) qv += __shfl_xor(qv, m, 64);
    float rstd = rsqrtf(qv * 0.00390625f + 1e-5f);
    const float4 gg = *(const float4*)&gw[lane * 4];
    const float4 bb = *(const float4*)&bw[lane * 4];
    uint2 u;
    u.x = f2bf(d0 * rstd * gg.x + bb.x) | ((unsigned)f2bf(d1 * rstd * gg.y + bb.y) << 16);
    u.y = f2bf(d2 * rstd * gg.z + bb.z) | ((unsigned)f2bf(d3 * rstd * gg.w + bb.w) << 16);
    *(uint2*)&out[(size_t)row * 256 + lane * 4] = u;
}

// ---------------- fused attention v5 ----------------
// grid (128 qtiles, 8 heads), 256 thr = 4 waves; each wave owns 32 queries
// (2 Q-fragments qfA/qfB sharing K/V loads). No LDS, no barriers.
// Swapped QK^T: mfma(K,Q) -> lane(l15,g) holds P[q=l15][keys 4g..4g+3, 16+4g..+3]
// packed via v_perm RTZ -- a valid PV A-fragment under the key permutation;
// V is STORED in that permutation, so its B-fragment is one 16B load/row.
// Denominator = ones-row MFMA. exp2 = raw v_exp_f32.
// __launch_bounds__(256,4): 128-VGPR budget so the 2-deep prefetch ring
// (12 loads in flight) stays in registers.
__global__ __launch_bounds__(256, 4) void attn_kernel(
    const bf16* __restrict__ qh, const bf16* __restrict__ kh,
    const bf16* __restrict__ vt, bf16* __restrict__ obf)
{
    const int tile = blockIdx.x, h = blockIdx.y;
    const int row0 = tile << 7;                 // 128 queries per block
    const int b = (row0 < 2048) ? 0 : (row0 < 8192) ? 1 : (row0 < 11264) ? 2 : 3;
    const int tid = threadIdx.x, lane = tid & 63, w = tid >> 6;
    const int l15 = lane & 15, g = lane >> 4;
    const int qbase = row0 + (w << 5);          // 32 queries per wave
    const int bh = (b << 3) + h;

    bf16x8 qfA = *(const bf16x8*)&qh[(size_t)(qbase + l15) * 256 + h * 32 + g * 8];
    bf16x8 qfB = *(const bf16x8*)&qh[(size_t)(qbase + 16 + l15) * 256 + h * 32 + g * 8];

    // ones fragment: B-col 0 (l15==0) all 1.0 -> col 0 of o2 = sum over keys
    bf16x8 ones;
    {
        unsigned ov = (l15 == 0) ? 0x3f803f80u : 0u;
        unsigned* op = (unsigned*)&ones;
        op[0] = ov; op[1] = ov; op[2] = ov; op[3] = ov;
    }

    f32x4 o0A = {0.f,0.f,0.f,0.f}, o1A = o0A, o2A = o0A;
    f32x4 o0B = o0A, o1B = o0A, o2B = o0A;
    const f32x4 z = {0.f, 0.f, 0.f, 0.f};

    const bf16* kp  = kh + ((size_t)bh * 1024 + l15) * 32 + g * 8;
    const bf16* vp0 = vt + ((size_t)bh * 32 + l15) * 1024 + (g << 3);  // d = l15
    const bf16* vp1 = vp0 + 16 * 1024;                                  // d = 16+l15

    // prologue: stage iterations 0 and 1 (K tile base advances 1024 elems/iter)
    bf16x8 cK0 = *(const bf16x8*)(kp);
    bf16x8 cK1 = *(const bf16x8*)(kp + 512);
    bf16x8 cV0 = *(const bf16x8*)(vp0);
    bf16x8 cV1 = *(const bf16x8*)(vp1);
    bf16x8 nK0 = *(const bf16x8*)(kp + 1024);
    bf16x8 nK1 = *(const bf16x8*)(kp + 1536);
    bf16x8 nV0 = *(const bf16x8*)(vp0 + 32);
    bf16x8 nV1 = *(const bf16x8*)(vp1 + 32);

#pragma unroll 2
    for (int it = 0; it < 32; ++it) {
        // stage iteration it+2 (wraparound reload at the tail, discarded)
        const int fk = ((it + 2) & 31) << 5;
        bf16x8 fK0 = *(const bf16x8*)(kp + (size_t)fk * 32);
        bf16x8 fK1 = *(const bf16x8*)(kp + (size_t)fk * 32 + 512);
        bf16x8 fV0 = *(const bf16x8*)(vp0 + fk);
        bf16x8 fV1 = *(const bf16x8*)(vp1 + fk);

        f32x4 s0A = mfma16(cK0, qfA, z);
        f32x4 s1A = mfma16(cK1, qfA, z);
        f32x4 s0B = mfma16(cK0, qfB, z);
        f32x4 s1B = mfma16(cK1, qfB, z);

        uint4 pAu, pBu;
        pAu.x = pk_rtz(ex2(s0A[0]), ex2(s0A[1]));
        pAu.y = pk_rtz(ex2(s0A[2]), ex2(s0A[3]));
        pAu.z = pk_rtz(ex2(s1A[0]), ex2(s1A[1]));
        pAu.w = pk_rtz(ex2(s1A[2]), ex2(s1A[3]));
        pBu.x = pk_rtz(ex2(s0B[0]), ex2(s0B[1]));
        pBu.y = pk_rtz(ex2(s0B[2]), ex2(s0B[3]));
        pBu.z = pk_rtz(ex2(s1B[0]), ex2(s1B[1]));
        pBu.w = pk_rtz(ex2(s1B[2]), ex2(s1B[3]));
        union { uint4 u; bf16x8 v; } cA, cB;
        cA.u = pAu; cB.u = pBu;

        o0A = mfma16(cA.v, cV0, o0A);
        o1A = mfma16(cA.v, cV1, o1A);
        o2A = mfma16(cA.v, ones, o2A);
        o0B = mfma16(cB.v, cV0, o0B);
        o1B = mfma16(cB.v, cV1, o1B);
        o2B = mfma16(cB.v, ones, o2B);

        cK0 = nK0; cK1 = nK1; cV0 = nV0; cV1 = nV1;
        nK0 = fK0; nK1 = fK1; nV0 = fV0; nV1 = fV1;
    }

#pragma unroll
    for (int r = 0; r < 4; ++r) {
        float invA = 1.f / __shfl(o2A[r], g << 4, 64);   // denom(q=4g+r) at lane 16g
        float invB = 1.f / __shfl(o2B[r], g << 4, 64);
        size_t orowA = (size_t)(qbase + (g << 2) + r) * 256 + h * 32;
        size_t orowB = (size_t)(qbase + 16 + (g << 2) + r) * 256 + h * 32;
        obf[orowA + l15]      = __float2bfloat16(o0A[r] * invA);
        obf[orowA + 16 + l15] = __float2bfloat16(o1A[r] * invA);
        obf[orowB + l15]      = __float2bfloat16(o0B[r] * invB);
        obf[orowB + 16 + l15] = __float2bfloat16(o1B[r] * invB);
    }
}

// ---------------- launcher ----------------

extern "C" void kernel_launch(void* const* d_in, const int* in_sizes, int n_in,
                              void* d_out, int out_size, void* d_ws, size_t ws_size,
                              hipStream_t stream)
{
    const float* x      = (const float*)d_in[0];
    const float* q      = (const float*)d_in[1];
    const float* w_q    = (const float*)d_in[5];
    const float* w_kv   = (const float*)d_in[6];
    const float* sr_w   = (const float*)d_in[7];
    const float* sr_b   = (const float*)d_in[8];
    const float* ln_g   = (const float*)d_in[9];
    const float* ln_b   = (const float*)d_in[10];
    const float* proj_w = (const float*)d_in[11];
    const float* proj_b = (const float*)d_in[12];

    char* w = (char*)d_ws;
    bf16* qh   = (bf16*)(w + 0);           //  8,388,608
    bf16* wqT  = (bf16*)(w + 8388608);     //    131,072
    bf16* wkvT = (bf16*)(w + 8519680);     //    262,144
    bf16* wprT = (bf16*)(w + 8781824);     //    131,072
    bf16* wcv  = (bf16*)(w + 8912896);     //  2,097,152
    bf16* xln  = (bf16*)(w + 11010048);    //  2,097,152
    bf16* kh   = (bf16*)(w + 13107200);    //  2,097,152  (per-head K [bh][key][32])
    bf16* vt   = (bf16*)(w + 15204352);    //  2,097,152  (per-head V^T, key-permuted)
    bf16* obf  = (bf16*)(w + 17301504);    //  8,388,608 -> total 25,690,112
    // split-K partials [4][4096][256] f32 = 16 MB live in d_out (overwritten by out proj)
    float* partials = (float*)d_out;
    float* out = (float*)d_out;

    transpose_cast_kernel<<<256, 256, 0, stream>>>(w_q, wqT, 256, 256);
    transpose_cast_kernel<<<512, 256, 0, stream>>>(w_kv, wkvT, 256, 512);
    transpose_cast_kernel<<<256, 256, 0, stream>>>(proj_w, wprT, 256, 256);
    conv_w_kernel<<<4096, 256, 0, stream>>>(sr_w, wcv);

    // q proj (fused f32->bf16 cast of q) -> qh, pre-scaled by SCALE*log2e
    gemm_kernel<2, 0><<<1024, 256, 0, stream>>>(q, wqT, nullptr, qh, nullptr, nullptr,
                                                16384, 256, 256, 256);
    // conv as im2col GEMM (fused cast of x), split-K=4 -> partials in d_out
    gemm_kernel<1, 3><<<dim3(256, 4), 256, 0, stream>>>(x, wcv, nullptr, nullptr, partials,
                                                        nullptr, 4096, 256, 4096, 1024);
    // fused reduce(4 slices) + conv bias + LayerNorm -> xln bf16
    ln_kernel<<<1024, 256, 0, stream>>>(partials, sr_b, ln_g, ln_b, xln);
    // kv proj -> kh per-head [bh][key][32] and vt (key-permuted) [(b*8+h)*32+d][keyp]
    gemm_kernel<0, 2><<<512, 256, 0, stream>>>(xln, wkvT, nullptr, kh, nullptr, vt,
                                               4096, 512, 256, 256);
    attn_kernel<<<dim3(128, 8), 256, 0, stream>>>(qh, kh, vt, obf);
    // out proj -> d_out (f32, +bias)
    gemm_kernel<0, 1><<<1024, 256, 0, stream>>>(obf, wprT, proj_b, nullptr, out, nullptr,
                                                16384, 256, 256, 256);
}

// Round 8
// 129.931 us; speedup vs baseline: 1.2973x; 1.2973x over previous
//
#include <hip/hip_runtime.h>
#include <hip/hip_bf16.h>

// Pipeline: weight prep -> q cast + im2col cast of x -> qproj GEMM ->
//           conv-as-GEMM (A=xim bf16, split-K=4, partials in d_out) ->
//           fused reduce+bias+LN -> kvproj GEMM -> fused attention -> out proj.
// GEMM v3: T3-min 2-phase pipeline with __builtin_amdgcn_global_load_lds
//   (width 16, pre-swizzled per-lane global source, linear LDS dest,
//   one __syncthreads per K-step = vmcnt(0) drain) + XCD-chunked swizzle.
// Attention v5 (unchanged): zero LDS/barriers, register P, permuted V,
//   2-deep prefetch, raw v_exp_f32.
// Workspace requirement: ~68 MB.

using bf16 = __hip_bfloat16;
using f32x4 = __attribute__((ext_vector_type(4))) float;
using bf16x8 = __attribute__((ext_vector_type(8))) short;

#define DEVINL __device__ __forceinline__
#define AS1 __attribute__((address_space(1)))
#define AS3 __attribute__((address_space(3)))

DEVINL f32x4 mfma16(bf16x8 a, bf16x8 b, f32x4 c) {
    return __builtin_amdgcn_mfma_f32_16x16x32_bf16(a, b, c, 0, 0, 0);
}

DEVINL unsigned short f2bf(float f) {
    union { float f; unsigned u; } x; x.f = f;
    unsigned u = x.u;
    u += 0x7fffu + ((u >> 16) & 1u);   // RNE
    return (unsigned short)(u >> 16);
}

// pack two f32 -> two bf16 (RTZ) in one v_perm: low16 = trunc(a), high16 = trunc(b)
DEVINL unsigned pk_rtz(float a, float b) {
    return __builtin_amdgcn_perm(__float_as_uint(b), __float_as_uint(a), 0x07060302u);
}

DEVINL float ex2(float x) { return __builtin_amdgcn_exp2f(x); }   // raw v_exp_f32

// async global->LDS DMA, 16B per lane. lds dest must be wave-uniform base
// (HW deposits at base + lane*16). CK-style addrspace reinterpret casts:
// global flat == AS1 bitwise; LDS flat low-32 == AS3 offset (4GB-aligned aperture).
DEVINL void gl16(const bf16* g, bf16* l) {
    __builtin_amdgcn_global_load_lds(
        (const AS1 void*)(unsigned long long)(uintptr_t)g,
        (AS3 void*)(unsigned)(uintptr_t)l,
        16, 0, 0);
}

// ---------------- prep kernels ----------------

// f32 -> bf16, 8 elems/thread
__global__ __launch_bounds__(256) void cast_bf16_kernel(const float* __restrict__ in,
                                                        bf16* __restrict__ out, int n8) {
    int i = blockIdx.x * 256 + threadIdx.x;
    if (i >= n8) return;
    float4 a = ((const float4*)in)[i * 2];
    float4 b = ((const float4*)in)[i * 2 + 1];
    uint4 u;
    u.x = f2bf(a.x) | ((unsigned)f2bf(a.y) << 16);
    u.y = f2bf(a.z) | ((unsigned)f2bf(a.w) << 16);
    u.z = f2bf(b.x) | ((unsigned)f2bf(b.y) << 16);
    u.w = f2bf(b.z) | ((unsigned)f2bf(b.w) << 16);
    ((uint4*)out)[i] = u;
}

// im2col + cast: xim[pr][dydx*256+c] = x[b][(ii*4+dy)*128 + jj*4+dx][c]  (bf16)
// pr = b*1024 + ii*32 + jj. One 16B out chunk per thread (grid 8192x256 exact).
__global__ __launch_bounds__(256) void im2col_kernel(const float* __restrict__ x,
                                                     bf16* __restrict__ xim) {
    int m = blockIdx.x * 256 + threadIdx.x;    // chunk id: pr*512 + dydx*32 + cchunk
    int cc8 = (m & 31) << 3;
    int dydx = (m >> 5) & 15;
    int pr = m >> 9;
    int b = pr >> 10, pi = pr & 1023;
    int ii = pi >> 5, jj = pi & 31;
    int dy = dydx >> 2, dx = dydx & 3;
    int pos = ((ii << 2) + dy) * 128 + (jj << 2) + dx;
    const float* s = &x[(size_t)((b << 14) + pos) * 256 + cc8];
    float4 a = *(const float4*)s;
    float4 c = *(const float4*)(s + 4);
    uint4 u;
    u.x = f2bf(a.x) | ((unsigned)f2bf(a.y) << 16);
    u.y = f2bf(a.z) | ((unsigned)f2bf(a.w) << 16);
    u.z = f2bf(c.x) | ((unsigned)f2bf(c.y) << 16);
    u.w = f2bf(c.z) | ((unsigned)f2bf(c.w) << 16);
    *(uint4*)&xim[(size_t)m * 8] = u;
}

// out[n*K + k] = in[k*N + n]  (weight [K,N] -> [N,K] bf16)
__global__ __launch_bounds__(256) void transpose_cast_kernel(const float* __restrict__ in,
                                                             bf16* __restrict__ out, int K, int N) {
    int idx = blockIdx.x * 256 + threadIdx.x;
    if (idx >= K * N) return;
    int k = idx % K, n = idx / K;
    out[idx] = __float2bfloat16(in[k * N + n]);
}

// wcv[o*4096 + dydx*256 + c] = sr_w[o][c][dy][dx]   (OIHW, 4x4)
__global__ __launch_bounds__(256) void conv_w_kernel(const float* __restrict__ sr_w,
                                                     bf16* __restrict__ out) {
    int idx = blockIdx.x * 256 + threadIdx.x;   // exact grid: 4096*256 = 1048576
    int o = idx >> 12, rest = idx & 4095, dydx = rest >> 8, c = rest & 255;
    out[idx] = __float2bfloat16(sr_w[((o << 8) + c) * 16 + dydx]);
}

// ---------------- GEMM (all-bf16, global_load_lds 2-phase) ----------------
// C[M,N] = A[M,K] * WT[N,K]^T. 64x64 tile, BK=64, 4 waves (2x2 sub-tiles).
// Stage: per wave 2 A-chunks + 2 B-chunks of 1KB via global_load_lds; source
// column XOR-pre-swizzled, LDS linear; read side applies the same XOR.
// Loop: STAGE(buf^1, t+1) -> compute(buf) -> __syncthreads (vmcnt0+barrier).
// EMODE 0: out bf16 * SCALE*log2e. EMODE 1: out f32 + bias.
// EMODE 2: kv split -> k per-head [bh][key][32]; v transposed+key-permuted.
// EMODE 3: f32 partial (split-K slice blockIdx.y) into outf[ks][4096][256].
template<int EMODE>
__global__ __launch_bounds__(256, 4) void gemm_kernel(
    const bf16* __restrict__ A, const bf16* __restrict__ WT,
    const float* __restrict__ bias,
    bf16* __restrict__ outb, float* __restrict__ outf, bf16* __restrict__ out2,
    int M, int N, int K, int KS)
{
    __shared__ alignas(16) bf16 As[2][64 * 64];
    __shared__ alignas(16) bf16 Bs[2][64 * 64];
    // XCD-chunked swizzle: XCD (bx%8) gets a contiguous tm-range with all tn.
    const int cpx = gridDim.x >> 3;
    const int bx = (blockIdx.x & 7) * cpx + (blockIdx.x >> 3);
    const int ntn = N >> 6;
    const int tm = bx / ntn, tn = bx % ntn;
    const int tid = threadIdx.x, lane = tid & 63, wid = tid >> 6;
    const int l15 = lane & 15, g = lane >> 4;
    const int wm = (wid >> 1) << 5, wn = (wid & 1) << 5;
    f32x4 acc[2][2] = {};

    // per-lane staged chunk coords (chunk idx = (wid*2+j)*64 + lane)
    int r_[2], cs_[2];
#pragma unroll
    for (int j = 0; j < 2; ++j) {
        int idx = (wid * 2 + j) * 64 + lane;
        r_[j] = idx >> 3;
        cs_[j] = ((idx & 7) ^ (r_[j] & 7)) << 3;   // pre-swizzled source column
    }
    const bf16* Arow = &A[(size_t)(tm * 64) * K];
    const bf16* Brow = &WT[(size_t)(tn * 64) * K];

    const int kbeg = blockIdx.y * KS;
    const int nsteps = KS >> 6;

    // stage one 64x64xBK tile pair into buffer `buf` (async DMA, no VGPRs)
    auto stage = [&](int buf, int k0) {
#pragma unroll
        for (int j = 0; j < 2; ++j) {
            gl16(Arow + (size_t)r_[j] * K + (k0 + cs_[j]), &As[buf][(wid * 2 + j) * 512]);
            gl16(Brow + (size_t)r_[j] * K + (k0 + cs_[j]), &Bs[buf][(wid * 2 + j) * 512]);
        }
    };

    stage(0, kbeg);
    __syncthreads();                     // vmcnt(0) drain + barrier

    for (int t = 0; t < nsteps; ++t) {
        const int buf = t & 1;
        if (t + 1 < nsteps) stage(buf ^ 1, kbeg + (t + 1) * 64);  // in flight across compute
#pragma unroll
        for (int kk = 0; kk < 2; ++kk) {
            const int sw = l15 & 7;
            const int co = ((kk * 4 + g) ^ sw) << 3;
            bf16x8 a0 = *(const bf16x8*)&As[buf][(wm + l15) * 64 + co];
            bf16x8 a1 = *(const bf16x8*)&As[buf][(wm + 16 + l15) * 64 + co];
            bf16x8 b0 = *(const bf16x8*)&Bs[buf][(wn + l15) * 64 + co];
            bf16x8 b1 = *(const bf16x8*)&Bs[buf][(wn + 16 + l15) * 64 + co];
            acc[0][0] = mfma16(a0, b0, acc[0][0]);
            acc[0][1] = mfma16(a0, b1, acc[0][1]);
            acc[1][0] = mfma16(a1, b0, acc[1][0]);
            acc[1][1] = mfma16(a1, b1, acc[1][1]);
        }
        __syncthreads();                 // staged loads landed; reads of buf done
    }

    const float qscale = 0.1767766953f * 1.4426950409f;  // HD^-0.5 * log2(e)
#pragma unroll
    for (int mi = 0; mi < 2; ++mi)
#pragma unroll
    for (int ni = 0; ni < 2; ++ni)
#pragma unroll
    for (int r = 0; r < 4; ++r) {
        int row = tm * 64 + wm + mi * 16 + g * 4 + r;
        int col = tn * 64 + wn + ni * 16 + l15;
        float v = acc[mi][ni][r];
        if constexpr (EMODE == 0) {
            outb[(size_t)row * 256 + col] = __float2bfloat16(v * qscale);
        } else if constexpr (EMODE == 1) {
            outf[(size_t)row * 256 + col] = v + bias[col];
        } else if constexpr (EMODE == 2) {
            int bb = row >> 10, key = row & 1023;
            if (col < 256) {
                int hh = col >> 5, d = col & 31;
                outb[(size_t)(((bb << 3) + hh) * 1024 + key) * 32 + d] = __float2bfloat16(v);
            } else {
                int d = col - 256;
                // key-permuted position within its 32-block: PV B-fragment order
                int c = key & 31;
                int pos = (((c >> 2) & 3) << 3) + ((c >> 4) << 2) + (c & 3);
                int keyp = (key & ~31) | pos;
                out2[(size_t)(((bb << 3) + (d >> 5)) * 32 + (d & 31)) * 1024 + keyp] =
                    __float2bfloat16(v);
            }
        } else {
            outf[((size_t)blockIdx.y * 4096 + row) * 256 + col] = v;
        }
    }
}

// ------- fused split-K reduce + conv bias + LayerNorm (C=256, one wave/row) -------
__global__ __launch_bounds__(256) void ln_kernel(const float* __restrict__ pp,
                                                 const float* __restrict__ cb,
                                                 const float* __restrict__ gw,
                                                 const float* __restrict__ bw,
                                                 bf16* __restrict__ out) {
    int row = blockIdx.x * 4 + (threadIdx.x >> 6);
    int lane = threadIdx.x & 63;
    const size_t base = (size_t)row * 256 + lane * 4;
    float4 v = *(const float4*)&pp[base];
#pragma unroll
    for (int s = 1; s < 4; ++s) {
        const float4 t = *(const float4*)&pp[(size_t)s * (4096 * 256) + base];
        v.x += t.x; v.y += t.y; v.z += t.z; v.w += t.w;
    }
    const float4 cbv = *(const float4*)&cb[lane * 4];
    v.x += cbv.x; v.y += cbv.y; v.z += cbv.z; v.w += cbv.w;

    float s = v.x + v.y + v.z + v.w;
#pragma unroll
    for (int m = 1; m < 64; m <<= 1) s += __shfl_xor(s, m, 64);
    float mu = s * 0.00390625f;
    float d0 = v.x - mu, d1 = v.y - mu, d2 = v.z - mu, d3 = v.w - mu;
    float qv = d0 * d0 + d1 * d1 + d2 * d2 + d3 * d3;
#pragma unroll
    for (int m = 1; m < 64; m <<= 1) qv += __shfl_xor(qv, m, 64);
    float rstd = rsqrtf(qv * 0.00390625f + 1e-5f);
    const float4 gg = *(const float4*)&gw[lane * 4];
    const float4 bb = *(const float4*)&bw[lane * 4];
    uint2 u;
    u.x = f2bf(d0 * rstd * gg.x + bb.x) | ((unsigned)f2bf(d1 * rstd * gg.y + bb.y) << 16);
    u.y = f2bf(d2 * rstd * gg.z + bb.z) | ((unsigned)f2bf(d3 * rstd * gg.w + bb.w) << 16);
    *(uint2*)&out[(size_t)row * 256 + lane * 4] = u;
}

// ---------------- fused attention v5 (unchanged) ----------------
// grid (128 qtiles, 8 heads), 256 thr = 4 waves; each wave owns 32 queries.
// Zero LDS/barriers; register P (k-axis permutation invariance); V stored
// key-permuted; ones-row MFMA denominator; 2-deep register prefetch.
__global__ __launch_bounds__(256, 4) void attn_kernel(
    const bf16* __restrict__ qh, const bf16* __restrict__ kh,
    const bf16* __restrict__ vt, bf16* __restrict__ obf)
{
    const int tile = blockIdx.x, h = blockIdx.y;
    const int row0 = tile << 7;                 // 128 queries per block
    const int b = (row0 < 2048) ? 0 : (row0 < 8192) ? 1 : (row0 < 11264) ? 2 : 3;
    const int tid = threadIdx.x, lane = tid & 63, w = tid >> 6;
    const int l15 = lane & 15, g = lane >> 4;
    const int qbase = row0 + (w << 5);          // 32 queries per wave
    const int bh = (b << 3) + h;

    bf16x8 qfA = *(const bf16x8*)&qh[(size_t)(qbase + l15) * 256 + h * 32 + g * 8];
    bf16x8 qfB = *(const bf16x8*)&qh[(size_t)(qbase + 16 + l15) * 256 + h * 32 + g * 8];

    bf16x8 ones;
    {
        unsigned ov = (l15 == 0) ? 0x3f803f80u : 0u;
        unsigned* op = (unsigned*)&ones;
        op[0] = ov; op[1] = ov; op[2] = ov; op[3] = ov;
    }

    f32x4 o0A = {0.f,0.f,0.f,0.f}, o1A = o0A, o2A = o0A;
    f32x4 o0B = o0A, o1B = o0A, o2B = o0A;
    const f32x4 z = {0.f, 0.f, 0.f, 0.f};

    const bf16* kp  = kh + ((size_t)bh * 1024 + l15) * 32 + g * 8;
    const bf16* vp0 = vt + ((size_t)bh * 32 + l15) * 1024 + (g << 3);  // d = l15
    const bf16* vp1 = vp0 + 16 * 1024;                                  // d = 16+l15

    bf16x8 cK0 = *(const bf16x8*)(kp);
    bf16x8 cK1 = *(const bf16x8*)(kp + 512);
    bf16x8 cV0 = *(const bf16x8*)(vp0);
    bf16x8 cV1 = *(const bf16x8*)(vp1);
    bf16x8 nK0 = *(const bf16x8*)(kp + 1024);
    bf16x8 nK1 = *(const bf16x8*)(kp + 1536);
    bf16x8 nV0 = *(const bf16x8*)(vp0 + 32);
    bf16x8 nV1 = *(const bf16x8*)(vp1 + 32);

#pragma unroll 2
    for (int it = 0; it < 32; ++it) {
        const int fk = ((it + 2) & 31) << 5;
        bf16x8 fK0 = *(const bf16x8*)(kp + (size_t)fk * 32);
        bf16x8 fK1 = *(const bf16x8*)(kp + (size_t)fk * 32 + 512);
        bf16x8 fV0 = *(const bf16x8*)(vp0 + fk);
        bf16x8 fV1 = *(const bf16x8*)(vp1 + fk);

        f32x4 s0A = mfma16(cK0, qfA, z);
        f32x4 s1A = mfma16(cK1, qfA, z);
        f32x4 s0B = mfma16(cK0, qfB, z);
        f32x4 s1B = mfma16(cK1, qfB, z);

        uint4 pAu, pBu;
        pAu.x = pk_rtz(ex2(s0A[0]), ex2(s0A[1]));
        pAu.y = pk_rtz(ex2(s0A[2]), ex2(s0A[3]));
        pAu.z = pk_rtz(ex2(s1A[0]), ex2(s1A[1]));
        pAu.w = pk_rtz(ex2(s1A[2]), ex2(s1A[3]));
        pBu.x = pk_rtz(ex2(s0B[0]), ex2(s0B[1]));
        pBu.y = pk_rtz(ex2(s0B[2]), ex2(s0B[3]));
        pBu.z = pk_rtz(ex2(s1B[0]), ex2(s1B[1]));
        pBu.w = pk_rtz(ex2(s1B[2]), ex2(s1B[3]));
        union { uint4 u; bf16x8 v; } cA, cB;
        cA.u = pAu; cB.u = pBu;

        o0A = mfma16(cA.v, cV0, o0A);
        o1A = mfma16(cA.v, cV1, o1A);
        o2A = mfma16(cA.v, ones, o2A);
        o0B = mfma16(cB.v, cV0, o0B);
        o1B = mfma16(cB.v, cV1, o1B);
        o2B = mfma16(cB.v, ones, o2B);

        cK0 = nK0; cK1 = nK1; cV0 = nV0; cV1 = nV1;
        nK0 = fK0; nK1 = fK1; nV0 = fV0; nV1 = fV1;
    }

#pragma unroll
    for (int r = 0; r < 4; ++r) {
        float invA = 1.f / __shfl(o2A[r], g << 4, 64);   // denom(q=4g+r) at lane 16g
        float invB = 1.f / __shfl(o2B[r], g << 4, 64);
        size_t orowA = (size_t)(qbase + (g << 2) + r) * 256 + h * 32;
        size_t orowB = (size_t)(qbase + 16 + (g << 2) + r) * 256 + h * 32;
        obf[orowA + l15]      = __float2bfloat16(o0A[r] * invA);
        obf[orowA + 16 + l15] = __float2bfloat16(o1A[r] * invA);
        obf[orowB + l15]      = __float2bfloat16(o0B[r] * invB);
        obf[orowB + 16 + l15] = __float2bfloat16(o1B[r] * invB);
    }
}

// ---------------- launcher ----------------

extern "C" void kernel_launch(void* const* d_in, const int* in_sizes, int n_in,
                              void* d_out, int out_size, void* d_ws, size_t ws_size,
                              hipStream_t stream)
{
    const float* x      = (const float*)d_in[0];
    const float* q      = (const float*)d_in[1];
    const float* w_q    = (const float*)d_in[5];
    const float* w_kv   = (const float*)d_in[6];
    const float* sr_w   = (const float*)d_in[7];
    const float* sr_b   = (const float*)d_in[8];
    const float* ln_g   = (const float*)d_in[9];
    const float* ln_b   = (const float*)d_in[10];
    const float* proj_w = (const float*)d_in[11];
    const float* proj_b = (const float*)d_in[12];

    char* w = (char*)d_ws;
    bf16* xim  = (bf16*)(w + 0);           // 33,554,432  (im2col bf16 [4096][4096])
    bf16* q_bf = (bf16*)(w + 33554432);    //  8,388,608
    bf16* qh   = (bf16*)(w + 41943040);    //  8,388,608
    bf16* wqT  = (bf16*)(w + 50331648);    //    131,072
    bf16* wkvT = (bf16*)(w + 50462720);    //    262,144
    bf16* wprT = (bf16*)(w + 50724864);    //    131,072
    bf16* wcv  = (bf16*)(w + 50855936);    //  2,097,152
    bf16* xln  = (bf16*)(w + 52953088);    //  2,097,152
    bf16* kh   = (bf16*)(w + 55050240);    //  2,097,152  (per-head K [bh][key][32])
    bf16* vt   = (bf16*)(w + 57147392);    //  2,097,152  (per-head V^T, key-permuted)
    bf16* obf  = (bf16*)(w + 59244544);    //  8,388,608 -> total 67,633,152
    // split-K partials [4][4096][256] f32 = 16 MB live in d_out (overwritten by out proj)
    float* partials = (float*)d_out;
    float* out = (float*)d_out;

    transpose_cast_kernel<<<256, 256, 0, stream>>>(w_q, wqT, 256, 256);
    transpose_cast_kernel<<<512, 256, 0, stream>>>(w_kv, wkvT, 256, 512);
    transpose_cast_kernel<<<256, 256, 0, stream>>>(proj_w, wprT, 256, 256);
    conv_w_kernel<<<4096, 256, 0, stream>>>(sr_w, wcv);
    cast_bf16_kernel<<<2048, 256, 0, stream>>>(q, q_bf, 524288);
    im2col_kernel<<<8192, 256, 0, stream>>>(x, xim);

    // q proj -> qh (pre-scaled by SCALE*log2e)
    gemm_kernel<0><<<1024, 256, 0, stream>>>(q_bf, wqT, nullptr, qh, nullptr, nullptr,
                                             16384, 256, 256, 256);
    // conv as GEMM on xim, split-K=4 -> partials in d_out
    gemm_kernel<3><<<dim3(256, 4), 256, 0, stream>>>(xim, wcv, nullptr, nullptr, partials,
                                                     nullptr, 4096, 256, 4096, 1024);
    // fused reduce(4 slices) + conv bias + LayerNorm -> xln bf16
    ln_kernel<<<1024, 256, 0, stream>>>(partials, sr_b, ln_g, ln_b, xln);
    // kv proj -> kh per-head [bh][key][32] and vt (key-permuted) [(b*8+h)*32+d][keyp]
    gemm_kernel<2><<<512, 256, 0, stream>>>(xln, wkvT, nullptr, kh, nullptr, vt,
                                            4096, 512, 256, 256);
    attn_kernel<<<dim3(128, 8), 256, 0, stream>>>(qh, kh, vt, obf);
    // out proj -> d_out (f32, +bias)
    gemm_kernel<1><<<1024, 256, 0, stream>>>(obf, wprT, proj_b, nullptr, out, nullptr,
                                             16384, 256, 256, 256);
}